// Round 5
// baseline (190.162 us; speedup 1.0000x reference)
//
#include <hip/hip_runtime.h>
#include <hip/hip_bf16.h>
#include <stdint.h>

#define FEATURES 256
#define SYMBOLS  1024
#define NPIX     65536        // 16*64*64
#define M_TILE   128
#define THREADS  512          // 8 waves: wm = wave>>1 (32-row band), wn = wave&1 (64-col half)
#define A_BYTES  32768        // A image: 128 rows x 256 B fp8, swizzled (own region, reused per iter)
#define TILE_BYTES 16384      // B tile: 128 syms x 128 feats fp8, pre-swizzled DMA image
#define NBUFS    4            // 4-deep B rotation
#define EXTRA_BYTES 6144      // mslot[256](1K) + codes[128](512B) + sspart(32B) + wlds[1024](4K)
#define SMEM_BYTES (A_BYTES + NBUFS * TILE_BYTES + EXTRA_BYTES)   // 102 KB -> 1 block/CU

typedef float f32x4  __attribute__((ext_vector_type(4)));
typedef float f32x16 __attribute__((ext_vector_type(16)));

// async global->LDS DMA, 16 B per lane; LDS dest = uniform base + lane*16
__device__ __forceinline__ void gld_lds16(const void* g, void* l) {
    __builtin_amdgcn_global_load_lds(
        (const __attribute__((address_space(1))) unsigned int*)g,
        (__attribute__((address_space(3))) unsigned int*)l, 16, 0, 0);
}

// pack 4 fp32 -> 4 fp8 e4m3 (OCP), byte j = element j   [validated: absmax 1.95e-3]
__device__ __forceinline__ uint32_t pack_fp8x4(float a, float b, float c, float d) {
    uint32_t u = 0;
    u = __builtin_amdgcn_cvt_pk_fp8_f32(a, b, u, false);
    u = __builtin_amdgcn_cvt_pk_fp8_f32(c, d, u, true);
    return u;
}

// ---- prep: fp8 DMA-image codebook (x256 scale keeps e4m3 normal), wnorm+1 bias, dev=0 ----
__global__ __launch_bounds__(64) void vq_prep(const float* __restrict__ W,
                                              char* __restrict__ Wt,
                                              float* __restrict__ wnorm,
                                              float* __restrict__ devslot) {
    int s = blockIdx.x;
    int lane = threadIdx.x;
    int n  = s & 127;
    int nc = s >> 7;
    f32x4 v = ((const f32x4*)(W + (size_t)s * FEATURES))[lane];
    float ss = v[0]*v[0] + v[1]*v[1] + v[2]*v[2] + v[3]*v[3];
    #pragma unroll
    for (int off = 32; off > 0; off >>= 1) ss += __shfl_xor(ss, off);
    if (lane == 0) wnorm[s] = ss + 1.0f;          // +1 bias: keys strictly positive
    if (s == 0 && lane == 0) *devslot = 0.f;

    if (lane < 32) {
        int kt = lane >> 4;          // 0..1
        int u  = lane & 15;          // 8-B unit within the 128-B tile row
        const float* src = W + (size_t)s * FEATURES + kt * 128 + (u >> 1) * 16 + (u & 1) * 8;
        uint32_t a = pack_fp8x4(256.f*src[0], 256.f*src[1], 256.f*src[2], 256.f*src[3]);
        uint32_t b = pack_fp8x4(256.f*src[4], 256.f*src[5], 256.f*src[6], 256.f*src[7]);
        uint2 w2 = {a, b};
        *(uint2*)(Wt + (size_t)(nc * 2 + kt) * TILE_BYTES + n * 128 + ((u ^ (n & 15)) * 8)) = w2;
    }
}

// ---- main: persistent 2-M-tile pipeline. Global step g = it*16 + tt, tile = g&15,
// buffer = (g+2)&3. pf(g+4) issued at step g (after barrier: buf last read at step g).
// it0 K-loop also loads x(t1) into regs as 2-load chunks at g=0..7; it0's gather is
// issued between the K-loops so its stores drain under K(t1)'s MFMAs.
// vmcnt tables derived from per-wave FIFO retire order (2 ops/pf, 2/chunk, 32/gather):
//   it0: g1:6 g2:8 g3..8:10 g9:8 g10:6 g11..14:4 (g0,g15: none)
//   pre-K(t1): vmcnt(38) = pf17,18,19(6)+gather(32) newer than pf16
//   it1: g16..18:36 g19..28:4 g29:2 g30:0 (g31: none)
__global__ __launch_bounds__(THREADS)
__attribute__((amdgpu_waves_per_eu(2, 2)))   // 1 block/CU, 2 waves/EU, 256-VGPR budget
void vq_main(
        const float*  __restrict__ x,
        const float*  __restrict__ W,
        const char*   __restrict__ Wt,
        const float*  __restrict__ wnorm,
        float*        __restrict__ out,
        float*        __restrict__ devslot) {
    extern __shared__ char smem[];
    const int t    = threadIdx.x;
    const int lane = t & 63;
    const int wave = t >> 6;             // 0..7
    const int l32  = lane & 31;
    const int half = lane >> 5;          // k-half within a 16-K step
    const int wm   = wave >> 1;          // 0..3: 32-pixel-row band
    const int wn   = wave & 1;           // 0..1: 64-symbol-col half
    const int m0   = blockIdx.x * (2 * M_TILE);
    const float scale = 1.25f / ((float)NPIX * (float)FEATURES);

    char* const bufs = smem + A_BYTES;
    uint32_t* mslot = (uint32_t*)(smem + A_BYTES + NBUFS * TILE_BYTES);      // [2][128]
    int*      codes = (int*)(smem + A_BYTES + NBUFS * TILE_BYTES + 1024);    // [128]
    float*    sspart = (float*)(smem + A_BYTES + NBUFS * TILE_BYTES + 1536); // [8]
    float*    wlds  = (float*)(smem + A_BYTES + NBUFS * TILE_BYTES + 2048);  // [1024]

    auto prefetch = [&](int g) {         // tile (g&15) -> buf ((g+2)&3), 2 DMA ops/wave
        const char* gsrc = Wt + (size_t)(g & 15) * TILE_BYTES;
        char* dst = bufs + (((g + 2) & 3) * TILE_BYTES);
        #pragma unroll
        for (int j = 0; j < 2; ++j) {
            int i = wave * 2 + j;        // 16 instrs x 1 KB
            gld_lds16(gsrc + i * 1024 + lane * 16, dst + i * 1024);
        }
    };

    // pack 16 reg-held float4 -> A image (row r = 256 B = 32 8-B units, phys u^(r&31))
    auto pack_stage = [&](const f32x4* xvp) -> float {
        float ss = 0.f;
        #pragma unroll
        for (int i = 0; i < 16; ++i) {
            int idx = i * THREADS + t;
            int row = idx >> 6;          // wave-uniform
            int k4  = idx & 63;
            f32x4 v = xvp[i];
            ss += v[0]*v[0] + v[1]*v[1] + v[2]*v[2] + v[3]*v[3];
            uint32_t pk = pack_fp8x4(v[0], v[1], v[2], v[3]);
            int u = k4 >> 1;
            *(uint32_t*)(smem + row * 256 + ((u ^ (row & 31)) * 8) + (k4 & 1) * 4) = pk;
        }
        return ss;
    };

    prefetch(0); prefetch(1); prefetch(2); prefetch(3);   // fly under the stage-A loads

    const f32x4* xblk0 = (const f32x4*)(x + (size_t)m0 * FEATURES);
    const f32x4* xblk1 = (const f32x4*)(x + (size_t)(m0 + M_TILE) * FEATURES);
    f32x4 xv[16];
    #pragma unroll
    for (int i = 0; i < 16; ++i) xv[i] = xblk0[i * THREADS + t];
    wlds[t] = wnorm[t];                  // LDS wnorm copy keeps in-loop vmcnt stream clean
    wlds[t + 512] = wnorm[t + 512];
    float ssacc = pack_stage(xv);
    __syncthreads();                     // drains ALL vmem (pf0..3, x, wnorm); A visible

    long af[16];
    auto extract_af = [&]() {            // af[s] = 8 fp8 of row (wm*32+l32), kstep s
        int r = wm * 32 + l32;
        #pragma unroll
        for (int s = 0; s < 16; ++s)
            af[s] = *(const long*)(smem + r * 256 + (((s * 2 + half) ^ l32) * 8));
    };
    extract_af();

    uint32_t best[16];
    #pragma unroll
    for (int j = 0; j < 16; ++j) best[j] = 0xFFFFFFFFu;
    const int n0 = wn * 64 + l32;        // tile-local B rows for this lane
    const int n1 = wn * 64 + 32 + l32;
    float bvacc = 0.f;

    auto epi = [&](int nc, const f32x16& acc0, const f32x16& acc1) {
        // score = (1 + wnorm) - (2/256)*acc > 0 -> float bits monotone as uint
        int nb0 = nc * 128 + wn * 64 + l32;
        float w0 = wlds[nb0 & 1023], w1 = wlds[(nb0 + 32) & 1023];
        #pragma unroll
        for (int r = 0; r < 16; ++r) {
            float v0 = __builtin_fmaf(-0.0078125f, acc0[r], w0);
            float v1 = __builtin_fmaf(-0.0078125f, acc1[r], w1);
            uint32_t k0 = (__float_as_uint(v0) & 0xFFFFFC00u) | (uint32_t)nb0;
            uint32_t k1 = (__float_as_uint(v1) & 0xFFFFFC00u) | (uint32_t)(nb0 + 32);
            uint32_t m  = k0 < k1 ? k0 : k1;
            best[r] = best[r] < m ? best[r] : m;
        }
    };

    // merge argmin across lanes/waves, write codes, accumulate bv, gather out-rows
    auto merge_and_gather = [&](float* outp) {
        #pragma unroll
        for (int r = 0; r < 16; ++r) {
            uint32_t v = best[r];
            #pragma unroll
            for (int off = 1; off < 32; off <<= 1) {
                uint32_t ov = (uint32_t)__shfl_xor((int)v, off);
                if (ov < v) v = ov;
            }
            best[r] = v;
        }
        if (l32 == 0) {
            #pragma unroll
            for (int r = 0; r < 16; ++r) {
                int row = wm * 32 + (r & 3) + 8 * (r >> 2) + 4 * half;
                mslot[wn * 128 + row] = best[r];
            }
        }
        asm volatile("s_waitcnt lgkmcnt(0)" ::: "memory");
        __builtin_amdgcn_s_barrier();
        if (t < 128) {
            uint32_t s0 = mslot[t], s1 = mslot[128 + t];
            uint32_t s = (s1 < s0) ? s1 : s0;
            codes[t] = (int)(s & 1023u);
            bvacc += __uint_as_float(s & 0xFFFFFC00u);   // 1 + wnorm[code] - 2*dot
        }
        asm volatile("s_waitcnt lgkmcnt(0)" ::: "memory");
        __builtin_amdgcn_s_barrier();
        // gather: exactly 16 dwordx4 loads + 16 dwordx4 stores per wave (vmcnt-counted)
        f32x4* oblk = (f32x4*)outp;
        #pragma unroll
        for (int h = 0; h < 2; ++h) {
            f32x4 gv[8];
            #pragma unroll
            for (int j = 0; j < 8; ++j) {
                int idx = (h * 8 + j) * THREADS + t;
                int row = idx >> 6;      // wave-uniform
                int code = __builtin_amdgcn_readfirstlane(codes[row]);
                gv[j] = ((const f32x4*)(W + (size_t)code * FEATURES))[idx & 63];
            }
            #pragma unroll
            for (int j = 0; j < 8; ++j)
                oblk[(h * 8 + j) * THREADS + t] = gv[j];
        }
    };

// one K step: MFMA burst from buf ((G+2)&3), counted-vmcnt wait (next tile resident),
// raw barrier (publish + buf-reuse fence), prefetch(G+4), optional x(t1) chunk.
#define K_STEP(G, WN, BAR, PFG, CH)                                                       \
    {                                                                                     \
        const char* buf_ = bufs + ((((G) + 2) & 3) * TILE_BYTES);                         \
        __builtin_amdgcn_s_setprio(1);                                                    \
        _Pragma("unroll")                                                                 \
        for (int s2 = 0; s2 < 8; ++s2) {                                                  \
            int u = s2 * 2 + half;                                                        \
            long b0 = *(const long*)(buf_ + n0 * 128 + ((u ^ (n0 & 15)) * 8));            \
            long b1 = *(const long*)(buf_ + n1 * 128 + ((u ^ (n1 & 15)) * 8));            \
            acc0 = __builtin_amdgcn_mfma_f32_32x32x16_fp8_fp8(af[((G) & 1) * 8 + s2], b0, acc0, 0, 0, 0); \
            acc1 = __builtin_amdgcn_mfma_f32_32x32x16_fp8_fp8(af[((G) & 1) * 8 + s2], b1, acc1, 0, 0, 0); \
        }                                                                                 \
        __builtin_amdgcn_s_setprio(0);                                                    \
        asm volatile("s_waitcnt vmcnt(" #WN ")" ::: "memory");                            \
        if (BAR) __builtin_amdgcn_s_barrier();                                            \
        if ((PFG) >= 0) prefetch(PFG);                                                    \
        if ((CH) >= 0) {                                                                  \
            xv[((CH) & 7) * 2]     = xblk1[(((CH) & 7) * 2) * THREADS + t];               \
            xv[((CH) & 7) * 2 + 1] = xblk1[(((CH) & 7) * 2 + 1) * THREADS + t];           \
        }                                                                                 \
    }

    // ---- K(t0): g = 0..15, x(t1) chunks at g=0..7 ----
    { f32x16 acc0 = {}, acc1 = {}; K_STEP(0, 63, 1,  4, 0) K_STEP(1,  6, 1,  5, 1) epi(0, acc0, acc1); }
    { f32x16 acc0 = {}, acc1 = {}; K_STEP(2,  8, 1,  6, 2) K_STEP(3, 10, 1,  7, 3) epi(1, acc0, acc1); }
    { f32x16 acc0 = {}, acc1 = {}; K_STEP(4, 10, 1,  8, 4) K_STEP(5, 10, 1,  9, 5) epi(2, acc0, acc1); }
    { f32x16 acc0 = {}, acc1 = {}; K_STEP(6, 10, 1, 10, 6) K_STEP(7, 10, 1, 11, 7) epi(3, acc0, acc1); }
    { f32x16 acc0 = {}, acc1 = {}; K_STEP(8, 10, 1, 12, -1) K_STEP(9,  8, 1, 13, -1) epi(4, acc0, acc1); }
    { f32x16 acc0 = {}, acc1 = {}; K_STEP(10, 6, 1, 14, -1) K_STEP(11, 4, 1, 15, -1) epi(5, acc0, acc1); }
    { f32x16 acc0 = {}, acc1 = {}; K_STEP(12, 4, 1, 16, -1) K_STEP(13, 4, 1, 17, -1) epi(6, acc0, acc1); }
    { f32x16 acc0 = {}, acc1 = {}; K_STEP(14, 4, 1, 18, -1) K_STEP(15, 63, 1, 19, -1) epi(7, acc0, acc1); }

    // ---- inter-tile: merge+gather(t0) (stores drain under K(t1)), stage(t1) from regs ----
    merge_and_gather(out + (size_t)m0 * FEATURES);
    ssacc += pack_stage(xv);             // A image for t1 (xv loaded by K(t0) chunks)
    {   // wave-reduce ss once, both iterations accumulated
        float ssw = ssacc;
        #pragma unroll
        for (int off = 32; off > 0; off >>= 1) ssw += __shfl_xor(ssw, off);
        if (lane == 0) sspart[wave] = ssw;
    }
    // pf16 resident (38 = pf17,18,19 + gather(32) newer) + A/sspart writes drained, publish
    asm volatile("s_waitcnt vmcnt(38) lgkmcnt(0)" ::: "memory");
    __builtin_amdgcn_s_barrier();
    extract_af();
    #pragma unroll
    for (int j = 0; j < 16; ++j) best[j] = 0xFFFFFFFFu;

    // ---- K(t1): g = 16..31 ----
    { f32x16 acc0 = {}, acc1 = {}; K_STEP(16, 36, 1, 20, -1) K_STEP(17, 36, 1, 21, -1) epi(0, acc0, acc1); }
    { f32x16 acc0 = {}, acc1 = {}; K_STEP(18, 36, 1, 22, -1) K_STEP(19,  4, 1, 23, -1) epi(1, acc0, acc1); }
    { f32x16 acc0 = {}, acc1 = {}; K_STEP(20,  4, 1, 24, -1) K_STEP(21,  4, 1, 25, -1) epi(2, acc0, acc1); }
    { f32x16 acc0 = {}, acc1 = {}; K_STEP(22,  4, 1, 26, -1) K_STEP(23,  4, 1, 27, -1) epi(3, acc0, acc1); }
    { f32x16 acc0 = {}, acc1 = {}; K_STEP(24,  4, 1, 28, -1) K_STEP(25,  4, 1, 29, -1) epi(4, acc0, acc1); }
    { f32x16 acc0 = {}, acc1 = {}; K_STEP(26,  4, 1, 30, -1) K_STEP(27,  4, 1, 31, -1) epi(5, acc0, acc1); }
    { f32x16 acc0 = {}, acc1 = {}; K_STEP(28,  4, 1, -1, -1) K_STEP(29,  2, 1, -1, -1) epi(6, acc0, acc1); }
    { f32x16 acc0 = {}, acc1 = {}; K_STEP(30,  0, 1, -1, -1) K_STEP(31, 63, 0, -1, -1) epi(7, acc0, acc1); }
#undef K_STEP

    merge_and_gather(out + (size_t)(m0 + M_TILE) * FEATURES);

    // ---- deviation: one atomic per wave 0/1 (bv over 2x64 rows) + one for ss ----
    if (t < 128) {
        float bv = bvacc;
        #pragma unroll
        for (int off = 32; off > 0; off >>= 1) bv += __shfl_xor(bv, off);
        if (lane == 0) atomicAdd(devslot, scale * (bv - 128.0f));   // un-bias: -1/pixel
        if (t == 0) {
            float sst = 0.f;
            #pragma unroll
            for (int w = 0; w < 8; ++w) sst += sspart[w];
            atomicAdd(devslot, scale * sst);
        }
    }
}

extern "C" void kernel_launch(void* const* d_in, const int* in_sizes, int n_in,
                              void* d_out, int out_size, void* d_ws, size_t ws_size,
                              hipStream_t stream) {
    const float* x = (const float*)d_in[0];
    const float* W = (const float*)d_in[1];
    float* out = (float*)d_out;

    char*  Wt    = (char*)d_ws;                                   // 256 KB fp8 tiles
    float* wnorm = (float*)((char*)d_ws + 16 * TILE_BYTES);       // 4 KB
    float* devslot = out + (size_t)NPIX * FEATURES;               // d_out tail

    hipFuncSetAttribute(reinterpret_cast<const void*>(vq_main),
                        hipFuncAttributeMaxDynamicSharedMemorySize, SMEM_BYTES);

    vq_prep<<<SYMBOLS, 64, 0, stream>>>(W, Wt, wnorm, devslot);
    vq_main<<<NPIX / (2 * M_TILE), THREADS, SMEM_BYTES, stream>>>(x, W, Wt, wnorm, out, devslot);
}